// Round 10
// baseline (415.815 us; speedup 1.0000x reference)
//
#include <hip/hip_runtime.h>
#include <hip/hip_bf16.h>
#include <math.h>

#define N_NODES 100000
#define DIM 128
#define NH 8
#define NC 16
#define E_EDGES 400000
#define LN_EPS 1e-3f
#define SCAN_B 1024
#define PROJ_GRID 512

typedef __attribute__((ext_vector_type(8))) short short8v;
typedef __attribute__((ext_vector_type(4))) short short4v;
typedef __attribute__((ext_vector_type(4))) float float4v;

__device__ __forceinline__ short bf16bits(float v) {
    __hip_bfloat16 b = __float2bfloat16(v);
    return *(short*)&b;
}

// unpack a uint holding 2 bf16 (lo, hi) into 2 floats
__device__ __forceinline__ void bf2x2(unsigned v, float& a, float& b) {
    a = __uint_as_float(v << 16);
    b = __uint_as_float(v & 0xffff0000u);
}

// ---------------- fused transposed weights (bf16) + fused biases -------------
// Wt[c][d], c in [0,640): sections of 128:
//  0: Wk (+bk)   1: Wm (+bm)
//  2: Wq·BD(Watt0)^T·prior0/4 (+bq fold)   3: same with Watt1/prior1
//  4: Wa (+ba)
// Score identity: (Watt k_src)·q_dst = k_src·(Watt^T q_dst) -> fold on q side.
// Message identity: sum w·(Wmsg m) = Wmsg·(sum w·m) -> applied in agg epilogue.
__global__ __launch_bounds__(128) void fuse_weights(
    const float* __restrict__ Wk, const float* __restrict__ bk,
    const float* __restrict__ Wm, const float* __restrict__ bm,
    const float* __restrict__ Wq, const float* __restrict__ bq,
    const float* __restrict__ Wa, const float* __restrict__ ba,
    const float* __restrict__ Watt0, const float* __restrict__ Watt1,
    const float* __restrict__ prior0, const float* __restrict__ prior1,
    __hip_bfloat16* __restrict__ Wt, float* __restrict__ bias)
{
    const int c = blockIdx.x;        // 0..639
    const int d = threadIdx.x;       // 0..127
    const int sec = c >> 7, j = c & 127, h = j >> 4, l = j & 15;
    float v = 0.f, b = 0.f;
    if (sec == 0)      { v = Wk[d * DIM + j]; b = bk[j]; }
    else if (sec == 1) { v = Wm[d * DIM + j]; b = bm[j]; }
    else if (sec == 4) { v = Wa[d * DIM + j]; b = ba[j]; }
    else {
        // qe_k = sum_l Watt[h][k][l] * q_{h,l}; contract SECOND index of Watt
        const float* W2 = (sec == 2) ? Watt0 : Watt1;
        float scale = ((sec == 2) ? prior0[h] : prior1[h]) * 0.25f;
        float s = 0.f, sb = 0.f;
        #pragma unroll
        for (int ll = 0; ll < NC; ++ll) {
            float w2 = W2[h * 256 + l * 16 + ll];   // Watt[h][k=l][ll]
            s  = fmaf(Wq[d * DIM + h * 16 + ll], w2, s);
            sb = fmaf(bq[h * 16 + ll], w2, sb);
        }
        v = s * scale; b = sb * scale;
    }
    Wt[(size_t)c * DIM + d] = __float2bfloat16(v);
    if (d == 0) bias[c] = b;
}

// ---------------- packed Wmsg table for agg epilogue -------------------------
// wmt[(s*32+g)][j] (uint, 2 bf16): j = k2*4+li packs Wmsg_s[h][2k2][lb+li]
// (lo) and Wmsg_s[h][2k2+1][lb+li] (hi), where h=g>>2, lb=(g&3)*4.
__global__ __launch_bounds__(256) void fuse_wmt(
    const float* __restrict__ Wmsg0, const float* __restrict__ Wmsg1,
    unsigned* __restrict__ wmt)
{
    const int tid = threadIdx.x;
    const int row = tid >> 2;            // 0..63 = s*32+g
    const int s = row >> 5, g = row & 31;
    const int h = g >> 2, lb = (g & 3) * 4;
    const float* W = s ? Wmsg1 : Wmsg0;
    #pragma unroll
    for (int jj = 0; jj < 8; ++jj) {
        int j = (tid & 3) * 8 + jj;
        int k2 = j >> 2, li = j & 3, l = lb + li;
        float wlo = W[h * 256 + (2 * k2) * 16 + l];
        float whi = W[h * 256 + (2 * k2 + 1) * 16 + l];
        unsigned pk = ((unsigned)(unsigned short)bf16bits(wlo))
                    | ((unsigned)(unsigned short)bf16bits(whi) << 16);
        wmt[row * 32 + j] = pk;
    }
}

// ---------------- proj: bf16 MFMA GEMM [N,128]@[128,512] ---------------------
// Persistent grid-stride, 8 waves, W register-resident, relaxed barrier.
// Outputs: kmr[N][512B] (32 groups of [k 4ch | m 4ch]) and qe[2N][128].
__global__ __launch_bounds__(512) void proj_mfma(
    const float* __restrict__ x,             // [N][128] fp32
    const __hip_bfloat16* __restrict__ Wt,   // [640][128]
    const float* __restrict__ bias,          // [640]
    __hip_bfloat16* __restrict__ kmr,        // [N][256] group-interleaved k|m
    __hip_bfloat16* __restrict__ qe)         // [2N][128] per-set folded q
{
    __shared__ __align__(16) short xs[2][32 * DIM];   // 2 x 8 KB
    const int tid = threadIdx.x;
    const int wave = tid >> 6, lane = tid & 63;
    const int quad = lane >> 4, mcol = lane & 15;
    const int nt = N_NODES / 32;                      // 3125

    // ---- hoist W fragments + bias into registers (once) -------------------
    short8v wf[4][4];
    float4v bv[4];
    #pragma unroll
    for (int s = 0; s < 4; ++s) {
        const int c0 = s * 128 + wave * 16;
        const short* wp = (const short*)Wt + (size_t)(c0 + mcol) * DIM + quad * 8;
        #pragma unroll
        for (int kb = 0; kb < 4; ++kb)
            wf[s][kb] = *(const short8v*)(wp + kb * 32);
        bv[s] = *(const float4v*)(bias + c0 + quad * 4);
    }

    // ---- staging geometry: thread -> (row 0..31, 16B chunk 0..15) ----------
    const int srow = tid >> 4, sc8 = tid & 15;
    const int swz = ((sc8 ^ (srow & 7)) * 8);         // XOR-swizzled chunk

    int t = blockIdx.x;
    if (t >= nt) return;

    // prologue: stage tile t into buf0, prefetch tile t+G into regs
    float4v f0 = *(const float4v*)(x + (size_t)(t * 32 + srow) * DIM + sc8 * 8);
    float4v f1 = *(const float4v*)(x + (size_t)(t * 32 + srow) * DIM + sc8 * 8 + 4);
    {
        short8v sv;
        #pragma unroll
        for (int j = 0; j < 4; ++j) { sv[j] = bf16bits(f0[j]); sv[j + 4] = bf16bits(f1[j]); }
        *(short8v*)(xs[0] + srow * DIM + swz) = sv;
    }
    {
        int nn = t + PROJ_GRID;
        if (nn < nt) {
            f0 = *(const float4v*)(x + (size_t)(nn * 32 + srow) * DIM + sc8 * 8);
            f1 = *(const float4v*)(x + (size_t)(nn * 32 + srow) * DIM + sc8 * 8 + 4);
        }
    }

    int cur = 0;
    for (; t < nt; t += PROJ_GRID) {
        // relaxed barrier: LDS writes visible, global stores NOT drained
        asm volatile("s_waitcnt lgkmcnt(0)" ::: "memory");
        __builtin_amdgcn_s_barrier();

        short8v b0[4], b1[4];
        #pragma unroll
        for (int kb = 0; kb < 4; ++kb) {
            const int ch = ((quad + kb * 4) ^ (mcol & 7)) * 8;
            b0[kb] = *(const short8v*)(xs[cur] + mcol * DIM + ch);
            b1[kb] = *(const short8v*)(xs[cur] + (mcol + 16) * DIM + ch);
        }

        const int r0 = t * 32;

        // ---- k|m pair -> one 16B store per lane per row-half --------------
        {
            float4v aK0 = {0.f,0.f,0.f,0.f}, aK1 = {0.f,0.f,0.f,0.f};
            float4v aM0 = {0.f,0.f,0.f,0.f}, aM1 = {0.f,0.f,0.f,0.f};
            #pragma unroll
            for (int kb = 0; kb < 4; ++kb) {
                aK0 = __builtin_amdgcn_mfma_f32_16x16x32_bf16(wf[0][kb], b0[kb], aK0, 0, 0, 0);
                aK1 = __builtin_amdgcn_mfma_f32_16x16x32_bf16(wf[0][kb], b1[kb], aK1, 0, 0, 0);
                aM0 = __builtin_amdgcn_mfma_f32_16x16x32_bf16(wf[1][kb], b0[kb], aM0, 0, 0, 0);
                aM1 = __builtin_amdgcn_mfma_f32_16x16x32_bf16(wf[1][kb], b1[kb], aM1, 0, 0, 0);
            }
            short8v o0, o1;
            #pragma unroll
            for (int g = 0; g < 4; ++g) {
                o0[g]     = bf16bits(aK0[g] + bv[0][g]);
                o0[g + 4] = bf16bits(aM0[g] + bv[1][g]);
                o1[g]     = bf16bits(aK1[g] + bv[0][g]);
                o1[g + 4] = bf16bits(aM1[g] + bv[1][g]);
            }
            short* dp = (short*)kmr + (size_t)(r0 + mcol) * 256
                      + (wave * 4 + quad) * 8;
            *(short8v*)dp              = o0;
            *(short8v*)(dp + 16 * 256) = o1;
        }

        // ---- qe sections (per-set folded q) -------------------------------
        #pragma unroll
        for (int e = 0; e < 2; ++e) {
            float4v a0v = {0.f,0.f,0.f,0.f}, a1v = {0.f,0.f,0.f,0.f};
            #pragma unroll
            for (int kb = 0; kb < 4; ++kb) {
                a0v = __builtin_amdgcn_mfma_f32_16x16x32_bf16(wf[2 + e][kb], b0[kb], a0v, 0, 0, 0);
                a1v = __builtin_amdgcn_mfma_f32_16x16x32_bf16(wf[2 + e][kb], b1[kb], a1v, 0, 0, 0);
            }
            short4v o0, o1;
            #pragma unroll
            for (int g = 0; g < 4; ++g) {
                o0[g] = bf16bits(a0v[g] + bv[2 + e][g]);
                o1[g] = bf16bits(a1v[g] + bv[2 + e][g]);
            }
            short* dp = (short*)qe + ((size_t)e * N_NODES + r0 + mcol) * DIM
                      + wave * 16 + quad * 4;
            *(short4v*)dp              = o0;
            *(short4v*)(dp + 16 * DIM) = o1;
        }

        // stage tile t+G into buf[cur^1]; prefetch t+2G
        int nn = t + PROJ_GRID;
        if (nn < nt) {
            short8v sv;
            #pragma unroll
            for (int j = 0; j < 4; ++j) { sv[j] = bf16bits(f0[j]); sv[j + 4] = bf16bits(f1[j]); }
            *(short8v*)(xs[cur ^ 1] + srow * DIM + swz) = sv;
            int n2 = nn + PROJ_GRID;
            if (n2 < nt) {
                f0 = *(const float4v*)(x + (size_t)(n2 * 32 + srow) * DIM + sc8 * 8);
                f1 = *(const float4v*)(x + (size_t)(n2 * 32 + srow) * DIM + sc8 * 8 + 4);
            }
        }
        cur ^= 1;
    }
}

// ---------------- CSR build ----------------
__global__ __launch_bounds__(256) void hist_kernel(
    const int* __restrict__ dst0, const int* __restrict__ dst1,
    int* __restrict__ counts)
{
    int e = blockIdx.x * 256 + threadIdx.x;
    if (e < E_EDGES) atomicAdd(&counts[dst0[e]], 1);
    int e1 = e - E_EDGES;
    if (e1 >= 0 && e1 < E_EDGES) atomicAdd(&counts[dst1[e1]], 1);
}

__global__ __launch_bounds__(SCAN_B) void scanA_kernel(
    const int* __restrict__ counts, int* __restrict__ row_ptr,
    int* __restrict__ bsum)
{
    __shared__ int buf[2][SCAN_B];
    int i = blockIdx.x * SCAN_B + threadIdx.x;
    int v = (i < N_NODES) ? counts[i] : 0;
    int cur = 0;
    buf[0][threadIdx.x] = v;
    __syncthreads();
    #pragma unroll
    for (int off = 1; off < SCAN_B; off <<= 1) {
        int t = buf[cur][threadIdx.x];
        int add = (threadIdx.x >= off) ? buf[cur][threadIdx.x - off] : 0;
        buf[cur ^ 1][threadIdx.x] = t + add;
        cur ^= 1;
        __syncthreads();
    }
    int inc = buf[cur][threadIdx.x];
    if (i < N_NODES) row_ptr[i] = inc - v;
    if (threadIdx.x == SCAN_B - 1) bsum[blockIdx.x] = inc;
}

// parallel exclusive scan of the (<=128) block sums, single block
__global__ __launch_bounds__(128) void scanB_kernel(int* __restrict__ bsum, int nblocks)
{
    __shared__ int buf[2][128];
    int t = threadIdx.x;
    int v = (t < nblocks) ? bsum[t] : 0;
    buf[0][t] = v;
    __syncthreads();
    int cur = 0;
    #pragma unroll
    for (int off = 1; off < 128; off <<= 1) {
        int a = buf[cur][t];
        if (t >= off) a += buf[cur][t - off];
        buf[cur ^ 1][t] = a;
        cur ^= 1;
        __syncthreads();
    }
    if (t < nblocks) bsum[t] = buf[cur][t] - v;   // exclusive
}

__global__ __launch_bounds__(SCAN_B) void scanC_kernel(
    int* __restrict__ row_ptr, int* __restrict__ cursor,
    const int* __restrict__ bsum)
{
    int i = blockIdx.x * SCAN_B + threadIdx.x;
    if (i < N_NODES) {
        int r = row_ptr[i] + bsum[blockIdx.x];
        row_ptr[i] = r;
        cursor[i] = r;
    }
}

__global__ __launch_bounds__(256) void scatter_kernel(
    const int* __restrict__ src0, const int* __restrict__ dst0,
    const int* __restrict__ src1, const int* __restrict__ dst1,
    int* __restrict__ cursor, unsigned int* __restrict__ eidx)
{
    int e = blockIdx.x * 256 + threadIdx.x;
    if (e < E_EDGES) {
        int d = dst0[e];
        int pos = atomicAdd(&cursor[d], 1);
        eidx[pos] = (unsigned int)src0[e];               // set 0
    }
    int e1 = e - E_EDGES;
    if (e1 >= 0 && e1 < E_EDGES) {
        int d = dst1[e1];
        int pos = atomicAdd(&cursor[d], 1);
        eidx[pos] = (unsigned int)src1[e1] | 0x80000000u; // set 1 flag in MSB
    }
}

// ---------------- aggregation + in-register Wmsg apply -----------------------
// Main loop (v8): pair scheme on kmr (51 MB), per-set raw-m accumulation,
// joint den. Epilogue (NEW): per-node BD(Wmsg) matvec in registers --
// gather 16 head-chans in 4-lane group (12 shfl), 64-FMA matvec per half
// (lanes 0-31: Wmsg0 x set0; 32-63: Wmsg1 x set1), cross-half add, invden,
// gelu, write pooled[N][128]. Replaces the 74us final-GEMM1 of v8.
__global__ __launch_bounds__(256) void agg_kernel(
    const char* __restrict__ kmr,       // [N][512B]
    const uint2* __restrict__ qe,       // [2N][32] uint2 (4 ch per lane)
    const unsigned* __restrict__ wmt,   // [64][32] packed Wmsg
    const int* __restrict__ row_ptr, const int* __restrict__ counts,
    const unsigned int* __restrict__ eidx,
    uint2* __restrict__ pooled)         // [N][32] uint2
{
    const int wave = threadIdx.x >> 6, lane = threadIdx.x & 63;
    const int n = blockIdx.x * 4 + wave;
    if (n >= N_NODES) return;
    const int start = row_ptr[n], cnt = counts[n];
    const int hi = lane >> 5;
    const int glane = lane & 31;
    const unsigned g16 = (unsigned)glane << 4;

    uint2 qu0 = qe[(size_t)n * 32 + glane];
    uint2 qu1 = qe[((size_t)N_NODES + n) * 32 + glane];
    float q00, q01, q02, q03, q10, q11, q12, q13;
    bf2x2(qu0.x, q00, q01); bf2x2(qu0.y, q02, q03);
    bf2x2(qu1.x, q10, q11); bf2x2(qu1.y, q12, q13);

    float b0 = 0.f, b1 = 0.f, b2 = 0.f, b3 = 0.f;   // set-0 accum
    float c0 = 0.f, c1 = 0.f, c2 = 0.f, c3 = 0.f;   // set-1 accum
    float den = 0.f;

#define PAIR_ACC(u, s1)                                                      \
    {                                                                        \
        float k0, k1, k2, k3, m0, m1, m2, m3;                                \
        bf2x2((u).x, k0, k1); bf2x2((u).y, k2, k3);                          \
        bf2x2((u).z, m0, m1); bf2x2((u).w, m2, m3);                          \
        float qa = (s1) ? q10 : q00, qb = (s1) ? q11 : q01;                  \
        float qc = (s1) ? q12 : q02, qd = (s1) ? q13 : q03;                  \
        float p = fmaf(k3, qd, fmaf(k2, qc, fmaf(k1, qb, k0 * qa)));         \
        p += __shfl_xor(p, 1, 64);                                           \
        p += __shfl_xor(p, 2, 64);                                           \
        float e = __expf(p);                                                 \
        den += e;                                                            \
        float e0 = (s1) ? 0.f : e, e1s = (s1) ? e : 0.f;                     \
        b0 = fmaf(e0, m0, b0); b1 = fmaf(e0, m1, b1);                        \
        b2 = fmaf(e0, m2, b2); b3 = fmaf(e0, m3, b3);                        \
        c0 = fmaf(e1s, m0, c0); c1 = fmaf(e1s, m1, c1);                      \
        c2 = fmaf(e1s, m2, c2); c3 = fmaf(e1s, m3, c3);                      \
    }

    int i = 0;
    for (; i + 8 <= cnt; i += 8) {
        unsigned ra = eidx[start + i + hi];
        unsigned rb = eidx[start + i + 2 + hi];
        unsigned rc = eidx[start + i + 4 + hi];
        unsigned rd = eidx[start + i + 6 + hi];
        uint4 ua = *(const uint4*)(kmr + ((size_t)(ra & 0x7fffffffu) << 9 | g16));
        uint4 ub = *(const uint4*)(kmr + ((size_t)(rb & 0x7fffffffu) << 9 | g16));
        uint4 uc = *(const uint4*)(kmr + ((size_t)(rc & 0x7fffffffu) << 9 | g16));
        uint4 ud = *(const uint4*)(kmr + ((size_t)(rd & 0x7fffffffu) << 9 | g16));
        PAIR_ACC(ua, (ra >> 31));
        PAIR_ACC(ub, (rb >> 31));
        PAIR_ACC(uc, (rc >> 31));
        PAIR_ACC(ud, (rd >> 31));
    }
    for (; i + 2 <= cnt; i += 2) {
        unsigned ra = eidx[start + i + hi];
        uint4 ua = *(const uint4*)(kmr + ((size_t)(ra & 0x7fffffffu) << 9 | g16));
        PAIR_ACC(ua, (ra >> 31));
    }
    if (i < cnt) {   // odd tail: both halves load edge; hi contributes 0
        unsigned ra = eidx[start + i];
        uint4 ua = *(const uint4*)(kmr + ((size_t)(ra & 0x7fffffffu) << 9 | g16));
        unsigned s1 = ra >> 31;
        float k0, k1, k2, k3, m0, m1, m2, m3;
        bf2x2(ua.x, k0, k1); bf2x2(ua.y, k2, k3);
        bf2x2(ua.z, m0, m1); bf2x2(ua.w, m2, m3);
        float qa = s1 ? q10 : q00, qb = s1 ? q11 : q01;
        float qc = s1 ? q12 : q02, qd = s1 ? q13 : q03;
        float p = fmaf(k3, qd, fmaf(k2, qc, fmaf(k1, qb, k0 * qa)));
        p += __shfl_xor(p, 1, 64);
        p += __shfl_xor(p, 2, 64);
        float e = hi ? 0.f : __expf(p);
        den += e;
        float e0 = s1 ? 0.f : e, e1s = s1 ? e : 0.f;
        b0 = fmaf(e0, m0, b0); b1 = fmaf(e0, m1, b1);
        b2 = fmaf(e0, m2, b2); b3 = fmaf(e0, m3, b3);
        c0 = fmaf(e1s, m0, c0); c1 = fmaf(e1s, m1, c1);
        c2 = fmaf(e1s, m2, c2); c3 = fmaf(e1s, m3, c3);
    }
#undef PAIR_ACC

    // combine pair halves (disjoint edges, same channel ownership)
    den += __shfl_xor(den, 32, 64);
    b0 += __shfl_xor(b0, 32, 64); b1 += __shfl_xor(b1, 32, 64);
    b2 += __shfl_xor(b2, 32, 64); b3 += __shfl_xor(b3, 32, 64);
    c0 += __shfl_xor(c0, 32, 64); c1 += __shfl_xor(c1, 32, 64);
    c2 += __shfl_xor(c2, 32, 64); c3 += __shfl_xor(c3, 32, 64);
    float inv = (den > 0.f) ? (1.f / den) : 0.f;

    // ---- load packed Wmsg for this (set=hi, lane) AFTER the loop ----------
    uint4 wv[8];
    {
        const uint4* wrow = (const uint4*)(wmt + (size_t)(hi * 32 + glane) * 32);
        #pragma unroll
        for (int j = 0; j < 8; ++j) wv[j] = wrow[j];
    }
#define WMR(idx) ( ((idx) & 3) == 0 ? wv[(idx) >> 2].x :                     \
                   ((idx) & 3) == 1 ? wv[(idx) >> 2].y :                     \
                   ((idx) & 3) == 2 ? wv[(idx) >> 2].z : wv[(idx) >> 2].w )

    // ---- gather 16 head-channels within the 4-lane group -------------------
    float t0 = hi ? c0 : b0, t1 = hi ? c1 : b1;
    float t2 = hi ? c2 : b2, t3 = hi ? c3 : b3;
    float u0 = __shfl_xor(t0, 1, 64), u1 = __shfl_xor(t1, 1, 64);
    float u2 = __shfl_xor(t2, 1, 64), u3 = __shfl_xor(t3, 1, 64);
    const bool pb0 = (glane & 1);
    float A0 = pb0 ? u0 : t0, A1 = pb0 ? u1 : t1, A2 = pb0 ? u2 : t2, A3 = pb0 ? u3 : t3;
    float A4 = pb0 ? t0 : u0, A5 = pb0 ? t1 : u1, A6 = pb0 ? t2 : u2, A7 = pb0 ? t3 : u3;
    float B0 = __shfl_xor(A0, 2, 64), B1 = __shfl_xor(A1, 2, 64);
    float B2 = __shfl_xor(A2, 2, 64), B3 = __shfl_xor(A3, 2, 64);
    float B4 = __shfl_xor(A4, 2, 64), B5 = __shfl_xor(A5, 2, 64);
    float B6 = __shfl_xor(A6, 2, 64), B7 = __shfl_xor(A7, 2, 64);
    const bool pb1 = (glane & 2);
    float h0 = pb1 ? B0 : A0, h1 = pb1 ? B1 : A1, h2 = pb1 ? B2 : A2, h3 = pb1 ? B3 : A3;
    float h4 = pb1 ? B4 : A4, h5 = pb1 ? B5 : A5, h6 = pb1 ? B6 : A6, h7 = pb1 ? B7 : A7;
    float h8 = pb1 ? A0 : B0, h9 = pb1 ? A1 : B1, h10 = pb1 ? A2 : B2, h11 = pb1 ? A3 : B3;
    float h12 = pb1 ? A4 : B4, h13 = pb1 ? A5 : B5, h14 = pb1 ? A6 : B6, h15 = pb1 ? A7 : B7;

    // ---- matvec: o_l = sum_k Wmsg[h][k][l] ch[k] (this half's set) ---------
    float o0 = 0.f, o1 = 0.f, o2 = 0.f, o3 = 0.f;
#define MV(k2, clo, chi_)                                                    \
    { float wl, wh;                                                          \
      bf2x2(WMR((k2) * 4 + 0), wl, wh);                                      \
      o0 = fmaf(chi_, wh, fmaf(clo, wl, o0));                                \
      bf2x2(WMR((k2) * 4 + 1), wl, wh);                                      \
      o1 = fmaf(chi_, wh, fmaf(clo, wl, o1));                                \
      bf2x2(WMR((k2) * 4 + 2), wl, wh);                                      \
      o2 = fmaf(chi_, wh, fmaf(clo, wl, o2));                                \
      bf2x2(WMR((k2) * 4 + 3), wl, wh);                                      \
      o3 = fmaf(chi_, wh, fmaf(clo, wl, o3)); }
    MV(0, h0, h1)   MV(1, h2, h3)   MV(2, h4, h5)   MV(3, h6, h7)
    MV(4, h8, h9)   MV(5, h10, h11) MV(6, h12, h13) MV(7, h14, h15)
#undef MV
#undef WMR

    // cross-half: pooled = set0 + set1; invden; gelu; store from lanes 0-31
    o0 += __shfl_xor(o0, 32, 64);
    o1 += __shfl_xor(o1, 32, 64);
    o2 += __shfl_xor(o2, 32, 64);
    o3 += __shfl_xor(o3, 32, 64);
    o0 *= inv; o1 *= inv; o2 *= inv; o3 *= inv;
    o0 = 0.5f * o0 * (1.f + erff(o0 * 0.70710678118654752f));
    o1 = 0.5f * o1 * (1.f + erff(o1 * 0.70710678118654752f));
    o2 = 0.5f * o2 * (1.f + erff(o2 * 0.70710678118654752f));
    o3 = 0.5f * o3 * (1.f + erff(o3 * 0.70710678118654752f));
    if (!hi) {
        uint2 o;
        o.x = ((unsigned)(unsigned short)bf16bits(o0))
            | ((unsigned)(unsigned short)bf16bits(o1) << 16);
        o.y = ((unsigned)(unsigned short)bf16bits(o2))
            | ((unsigned)(unsigned short)bf16bits(o3) << 16);
        pooled[(size_t)n * 32 + glane] = o;
    }
}

// ---------------- final: MFMA GEMM(Wa) -> skip -> LayerNorm ------------------
__global__ __launch_bounds__(256) void final_mfma(
    const __hip_bfloat16* __restrict__ pooled,  // [N][128] bf16, gelu applied
    const __hip_bfloat16* __restrict__ Wt,      // [640][128]; rows 512.. = Wa^T
    const float* __restrict__ bias,             // [640]; 512.. = ba
    const float* __restrict__ x,
    const float* __restrict__ skip, const float* __restrict__ gamma,
    const float* __restrict__ beta, float* __restrict__ out)
{
    __shared__ float hs[32][DIM];
    const int wave = threadIdx.x >> 6, lane = threadIdx.x & 63;
    const int quad = lane >> 4, mcol = lane & 15;
    const int r0 = blockIdx.x * 32;

    short8v a0[4], a1[4];
    const short* pp0 = (const short*)pooled + (size_t)(r0 + mcol) * DIM + quad * 8;
    const short* pp1 = pp0 + 16 * DIM;
    #pragma unroll
    for (int kb = 0; kb < 4; ++kb) {
        a0[kb] = *(const short8v*)(pp0 + kb * 32);
        a1[kb] = *(const short8v*)(pp1 + kb * 32);
    }
    const float alpha = 1.f / (1.f + expf(-skip[0]));

    #pragma unroll
    for (int t = 0; t < 2; ++t) {
        const int c0 = wave * 32 + t * 16;
        const short* wp = (const short*)Wt + (size_t)(512 + c0 + mcol) * DIM + quad * 8;
        float4v acc0 = {0.f, 0.f, 0.f, 0.f};
        float4v acc1 = {0.f, 0.f, 0.f, 0.f};
        #pragma unroll
        for (int kb = 0; kb < 4; ++kb) {
            short8v bfr = *(const short8v*)(wp + kb * 32);
            acc0 = __builtin_amdgcn_mfma_f32_16x16x32_bf16(a0[kb], bfr, acc0, 0, 0, 0);
            acc1 = __builtin_amdgcn_mfma_f32_16x16x32_bf16(a1[kb], bfr, acc1, 0, 0, 0);
        }
        const float bcol = bias[512 + c0 + mcol];
        const int cc = c0 + mcol;
        const int rq = quad * 4;
        #pragma unroll
        for (int g = 0; g < 4; ++g) {
            int rA = rq + g, rB = rq + 16 + g;
            hs[rA][cc] = alpha * (acc0[g] + bcol)
                       + (1.f - alpha) * x[(size_t)(r0 + rA) * DIM + cc];
            hs[rB][cc] = alpha * (acc1[g] + bcol)
                       + (1.f - alpha) * x[(size_t)(r0 + rB) * DIM + cc];
        }
    }
    __syncthreads();

    float gam0 = gamma[lane], gam1 = gamma[lane + 64];
    float bet0 = beta[lane],  bet1 = beta[lane + 64];
    for (int r = wave; r < 32; r += 4) {
        int row = r0 + r;
        float v0 = hs[r][lane], v1 = hs[r][lane + 64];
        float s = v0 + v1, s2 = v0 * v0 + v1 * v1;
        #pragma unroll
        for (int off = 1; off < 64; off <<= 1) {
            s  += __shfl_xor(s,  off, 64);
            s2 += __shfl_xor(s2, off, 64);
        }
        float mu = s * (1.f / 128.f);
        float var = s2 * (1.f / 128.f) - mu * mu;
        float rstd = rsqrtf(var + LN_EPS);
        out[(size_t)row * DIM + lane]      = (v0 - mu) * rstd * gam0 + bet0;
        out[(size_t)row * DIM + lane + 64] = (v1 - mu) * rstd * gam1 + bet1;
    }
}

extern "C" void kernel_launch(void* const* d_in, const int* in_sizes, int n_in,
                              void* d_out, int out_size, void* d_ws, size_t ws_size,
                              hipStream_t stream) {
    const float* x     = (const float*)d_in[0];
    const int*   src0  = (const int*)d_in[1];
    const int*   dst0  = (const int*)d_in[2];
    const int*   src1  = (const int*)d_in[3];
    const int*   dst1  = (const int*)d_in[4];
    const float* Wk    = (const float*)d_in[5];
    const float* bk    = (const float*)d_in[6];
    const float* Wm    = (const float*)d_in[7];
    const float* bm    = (const float*)d_in[8];
    const float* Wq    = (const float*)d_in[9];
    const float* bq    = (const float*)d_in[10];
    const float* Wa    = (const float*)d_in[11];
    const float* ba    = (const float*)d_in[12];
    const float* Watt0 = (const float*)d_in[13];
    const float* Wmsg0 = (const float*)d_in[14];
    const float* Watt1 = (const float*)d_in[15];
    const float* Wmsg1 = (const float*)d_in[16];
    const float* prior0= (const float*)d_in[17];
    const float* prior1= (const float*)d_in[18];
    const float* skip  = (const float*)d_in[19];
    const float* gamma = (const float*)d_in[20];
    const float* beta  = (const float*)d_in[21];
    float* out = (float*)d_out;

    // Workspace (~133 MB):
    //   Wt [640*128 bf16] | bias [640 f32] | wmt [2048 u32] | kmr [N*256 bf16]
    //   | qe [2N*128 bf16] | pooled [N*128 bf16] | counts/row_ptr/cursor
    //   | bsum | eidx [2E u32]
    char* wsb = (char*)d_ws;
    __hip_bfloat16* Wt    = (__hip_bfloat16*)wsb;  wsb += (size_t)640 * DIM * 2;
    float* bias           = (float*)wsb;           wsb += 640 * 4;
    unsigned* wmt         = (unsigned*)wsb;        wsb += 2048 * 4;
    __hip_bfloat16* kmr   = (__hip_bfloat16*)wsb;  wsb += (size_t)N_NODES * 256 * 2;
    __hip_bfloat16* qe    = (__hip_bfloat16*)wsb;  wsb += (size_t)2 * N_NODES * DIM * 2;
    __hip_bfloat16* pooled= (__hip_bfloat16*)wsb;  wsb += (size_t)N_NODES * DIM * 2;
    int* counts  = (int*)wsb;                      wsb += (size_t)N_NODES * 4;
    int* row_ptr = (int*)wsb;                      wsb += (size_t)N_NODES * 4;
    int* cursor  = (int*)wsb;                      wsb += (size_t)N_NODES * 4;
    int* bsum    = (int*)wsb;                      wsb += 128 * 4;
    unsigned int* eidx = (unsigned int*)wsb;

    hipMemsetAsync(counts, 0, (size_t)N_NODES * 4, stream);

    const int scan_blocks = (N_NODES + SCAN_B - 1) / SCAN_B;   // 98
    const int edge_blocks = (2 * E_EDGES + 255) / 256;         // 3125

    // CSR chain (independent of projections)
    hist_kernel<<<dim3(edge_blocks), dim3(256), 0, stream>>>(dst0, dst1, counts);
    scanA_kernel<<<dim3(scan_blocks), dim3(SCAN_B), 0, stream>>>(counts, row_ptr, bsum);
    scanB_kernel<<<dim3(1), dim3(128), 0, stream>>>(bsum, scan_blocks);
    scanC_kernel<<<dim3(scan_blocks), dim3(SCAN_B), 0, stream>>>(row_ptr, cursor, bsum);
    scatter_kernel<<<dim3(edge_blocks), dim3(256), 0, stream>>>(
        src0, dst0, src1, dst1, cursor, eidx);

    // Projections
    fuse_weights<<<dim3(640), dim3(128), 0, stream>>>(
        Wk, bk, Wm, bm, Wq, bq, Wa, ba,
        Watt0, Watt1, prior0, prior1, Wt, bias);
    fuse_wmt<<<dim3(1), dim3(256), 0, stream>>>(Wmsg0, Wmsg1, wmt);
    proj_mfma<<<dim3(PROJ_GRID), dim3(512), 0, stream>>>(
        x, Wt, bias, kmr, qe);

    agg_kernel<<<dim3((N_NODES + 3) / 4), dim3(256), 0, stream>>>(
        (const char*)kmr, (const uint2*)qe, wmt, row_ptr, counts, eidx,
        (uint2*)pooled);

    final_mfma<<<dim3(N_NODES / 32), dim3(256), 0, stream>>>(
        pooled, Wt, bias, x, skip, gamma, beta, out);
}